// Round 3
// baseline (393.248 us; speedup 1.0000x reference)
//
#include <hip/hip_runtime.h>

// 1024-point FFT of real input, batched 16384. Two-for-one packing:
// ONE WAVE per row-pair: z = x0 + i*x1, 64 lanes x 16 complex elements
// held in registers. Radix-4 DIF Stockham, 5 stages, merged in pairs:
//   stage A = (M=1, M=4) in-register
//   LDS exchange 1 (wave-private buffer, wave-synchronous fence)
//   stage B = (M=16, M=64) in-register
//   LDS exchange 2
//   stage C = (M=256, unit twiddles) in-place + conjugate-symmetry unpack
// Zero block-wide barriers in the pipeline (one __syncthreads for the
// shared twiddle table). Exchanges are wave-synchronous: lockstep wave64
// + "s_waitcnt lgkmcnt(0)" with memory clobber for compiler ordering.
//
// Merge algebra: lane T owns global indices {T + 64q}; radix-4 partners
// (+256p) are then lane-local for two consecutive stages. Twiddles match
// the verified 5-stage kernel exactly: w1 = tw1024[M*j], w2 = w1^2,
// w3 = w1*w2; all w1 indices <= 255 so a 256-entry table suffices.

#define N_FFT 1024
#define BATCH 16384
#define TPB   256   // 4 waves per block; 1 wave = 1 row-pair

typedef float f4 __attribute__((ext_vector_type(4)));

// LDS pad: +1 float2 per 16 slots
__device__ __forceinline__ int pad16(int a) { return a + (a >> 4); }

__device__ __forceinline__ float2 cmul(float2 a, float2 b) {
    return make_float2(a.x * b.x - a.y * b.y, a.x * b.y + a.y * b.x);
}
__device__ __forceinline__ float2 cadd(float2 a, float2 b) { return make_float2(a.x + b.x, a.y + b.y); }
__device__ __forceinline__ float2 csub(float2 a, float2 b) { return make_float2(a.x - b.x, a.y - b.y); }

// Wave-synchronous LDS fence: drain LDS queue + full compiler memory barrier.
#define LDS_FENCE() asm volatile("s_waitcnt lgkmcnt(0)" ::: "memory")

// Radix-4 DIF butterfly, twiddled; in-place: A<-y0, B<-y1, C<-y2, D<-y3.
__device__ __forceinline__ void bf4(float2& A, float2& B, float2& C, float2& D, float2 w1)
{
    float2 t0 = cadd(A, C), t1 = csub(A, C);
    float2 t2 = cadd(B, D);
    float2 t3 = make_float2(B.y - D.y, D.x - B.x);   // -i*(B-D)
    float2 w2 = cmul(w1, w1);
    float2 w3 = cmul(w1, w2);
    A = cadd(t0, t2);
    B = cmul(cadd(t1, t3), w1);
    C = cmul(csub(t0, t2), w2);
    D = cmul(csub(t1, t3), w3);
}
// Unit-twiddle variant (final stage).
__device__ __forceinline__ void bf4_nw(float2& A, float2& B, float2& C, float2& D)
{
    float2 t0 = cadd(A, C), t1 = csub(A, C);
    float2 t2 = cadd(B, D);
    float2 t3 = make_float2(B.y - D.y, D.x - B.x);
    A = cadd(t0, t2);
    B = cadd(t1, t3);
    C = csub(t0, t2);
    D = csub(t1, t3);
}

__global__ __launch_bounds__(TPB, 4) void fft1024_kernel(
    const float* __restrict__ x,
    const float* __restrict__ twr,   // w_1024^k re, k<512 (first 256 used)
    const float* __restrict__ twi,
    float* __restrict__ outr,
    float* __restrict__ outi)
{
    __shared__ __align__(16) float2 exbuf[4][1088];  // per-wave 1024 + pad
    __shared__ __align__(16) float2 tws[256];        // w_1024^k, k<256

    const int tid = threadIdx.x;
    const int T   = tid & 63;        // lane
    const int wv  = tid >> 6;        // wave in block
    float2* __restrict__ ex = exbuf[wv];

    // twiddle table (wave 0 only)
    if (tid < 64) {
        f4 re = reinterpret_cast<const f4*>(twr)[tid];
        f4 im = reinterpret_cast<const f4*>(twi)[tid];
        #pragma unroll
        for (int j = 0; j < 4; ++j)
            tws[4 * tid + j] = make_float2(re[j], im[j]);
    }

    const long long r0 = 2LL * (4LL * blockIdx.x + wv);  // even row; +1 = odd
    const float* __restrict__ x0 = x + r0 * N_FFT;
    const float* __restrict__ x1 = x0 + N_FFT;

    // lane T owns globals {T + 64q}: z[q] = x0[i] + i*x1[i]
    float2 z[16];
    #pragma unroll
    for (int q = 0; q < 16; ++q)
        z[q] = make_float2(x0[T + 64 * q], x1[T + 64 * q]);

    __syncthreads();   // tws ready (global-load latency overlaps the wait)

    // ---- stage A: M=1 then M=4, in-register ----
    // M=1: butterfly u at i0 = T+64u; inputs slots {u+4p}; y_p -> slot 4p+u (in-place)
    #pragma unroll
    for (int u = 0; u < 4; ++u)
        bf4(z[u], z[u + 4], z[u + 8], z[u + 12], tws[T + 64 * u]);
    // M=4: butterfly r at i0 = 4T+r; j = T for all r; outputs -> LDS natural index
    {
        float2 wA = tws[4 * T];
        #pragma unroll
        for (int r = 0; r < 4; ++r) {
            bf4(z[4 * r], z[4 * r + 1], z[4 * r + 2], z[4 * r + 3], wA);
            ex[pad16(16 * T + r)]      = z[4 * r];       // y0 -> 16T + r
            ex[pad16(16 * T + 4 + r)]  = z[4 * r + 1];   // y1 -> +4
            ex[pad16(16 * T + 8 + r)]  = z[4 * r + 2];   // y2 -> +8
            ex[pad16(16 * T + 12 + r)] = z[4 * r + 3];   // y3 -> +12
        }
    }
    LDS_FENCE();                       // writes visible wave-wide
    #pragma unroll
    for (int q = 0; q < 16; ++q)
        z[q] = ex[pad16(T + 64 * q)];
    LDS_FENCE();                       // all reads done before exchange-2 writes

    // ---- stage B: M=16 then M=64, in-register ----
    // M=16: butterfly u at i0 = T+64u; w1 = tw[16*(i0>>4)] = tw[i0 & ~15]
    #pragma unroll
    for (int u = 0; u < 4; ++u)
        bf4(z[u], z[u + 4], z[u + 8], z[u + 12], tws[(T + 64 * u) & ~15]);
    // M=64: butterfly p at i0 = 64a + 16p + b (a = T>>4, b = T&15); w1 = tw[64a]
    {
        float2 wB = tws[(T >> 4) << 6];
        const int base2 = ((T >> 4) << 8) + (T & 15);    // 256a + b
        #pragma unroll
        for (int p = 0; p < 4; ++p) {
            bf4(z[4 * p], z[4 * p + 1], z[4 * p + 2], z[4 * p + 3], wB);
            ex[pad16(base2 + 16 * p)]       = z[4 * p];      // y0 -> base
            ex[pad16(base2 + 16 * p + 64)]  = z[4 * p + 1];  // y1 -> +64
            ex[pad16(base2 + 16 * p + 128)] = z[4 * p + 2];  // y2 -> +128
            ex[pad16(base2 + 16 * p + 192)] = z[4 * p + 3];  // y3 -> +192
        }
    }
    LDS_FENCE();

    // ---- stage C: M=256, unit twiddles; lane-private in-place in LDS ----
    #pragma unroll
    for (int q = 0; q < 16; ++q)
        z[q] = ex[pad16(T + 64 * q)];
    #pragma unroll
    for (int u = 0; u < 4; ++u) {
        bf4_nw(z[u], z[u + 4], z[u + 8], z[u + 12]);
        ex[pad16(T + 64 * u)]       = z[u];        // Z(i0)
        ex[pad16(T + 64 * u + 256)] = z[u + 4];    // Z(i0+256)
        ex[pad16(T + 64 * u + 512)] = z[u + 8];    // Z(i0+512)
        ex[pad16(T + 64 * u + 768)] = z[u + 12];   // Z(i0+768)
    }
    LDS_FENCE();

    // ---- unpack two real-input spectra; lane T covers k in [16T, 16T+16) ----
    // Each lane writes full 64B lines of all 4 output streams -> nt-safe.
    f4* or0v = reinterpret_cast<f4*>(outr + r0 * N_FFT);
    f4* oi0v = reinterpret_cast<f4*>(outi + r0 * N_FFT);
    #pragma unroll
    for (int g = 0; g < 4; ++g) {
        f4 vr0, vi0, vr1, vi1;
        #pragma unroll
        for (int e = 0; e < 4; ++e) {
            const int k  = 16 * T + 4 * g + e;
            const int nk = (N_FFT - k) & (N_FFT - 1);
            float2 zk = ex[pad16(k)];
            float2 zn = ex[pad16(nk)];
            // X0 = (Z(k) + conj(Z(-k)))/2 ; X1 = -i*(Z(k) - conj(Z(-k)))/2
            vr0[e] = 0.5f * (zk.x + zn.x);
            vi0[e] = 0.5f * (zk.y - zn.y);
            vr1[e] = 0.5f * (zk.y + zn.y);
            vi1[e] = 0.5f * (zn.x - zk.x);
        }
        __builtin_nontemporal_store(vr0, or0v + 4 * T + g);          // row r0 real
        __builtin_nontemporal_store(vi0, oi0v + 4 * T + g);          // row r0 imag
        __builtin_nontemporal_store(vr1, or0v + 256 + 4 * T + g);    // row r0+1 real
        __builtin_nontemporal_store(vi1, oi0v + 256 + 4 * T + g);    // row r0+1 imag
    }
}

extern "C" void kernel_launch(void* const* d_in, const int* in_sizes, int n_in,
                              void* d_out, int out_size, void* d_ws, size_t ws_size,
                              hipStream_t stream) {
    // setup_inputs order:
    // 0:x 1:perm 2:fft_real 3:fft_imag 4..11: tw_{real,imag}_{0..3}
    const float* x   = (const float*)d_in[0];
    const float* twr = (const float*)d_in[10];  // 512 entries: w_1024^k real
    const float* twi = (const float*)d_in[11];  // 512 entries: w_1024^k imag
    float* outr = (float*)d_out;
    float* outi = outr + (size_t)BATCH * N_FFT;
    fft1024_kernel<<<BATCH / 8, TPB, 0, stream>>>(x, twr, twi, outr, outi);
}

// Round 4
// 207.100 us; speedup vs baseline: 1.8988x; 1.8988x over previous
//
#include <hip/hip_runtime.h>

// 1024-point FFT of real input, batched 16384. Two-for-one packing.
// Block = 256 threads = 4 waves; wave w owns ONE row-pair (rows 8b+2w,
// 8b+2w+1) as z = x0 + i*x1, 64 lanes x 16 complex elements in registers.
// Radix-4 DIF Stockham, 5 stages merged in pairs in-register:
//   stage-in (f4 coalesced loads -> LDS, wave-private region)
//   stage A = (M=1, M=4) in-register          [verified in R3]
//   LDS exchange 1
//   stage B = (M=16, M=64) in-register        [verified in R3]
//   LDS exchange 2
//   stage C = (M=256, unit twiddles) lane-private in-place
//   unpack via conjugate symmetry, lane-CONTIGUOUS f4 NT stores
//     (R3's 64B-strided stores caused 2.1x write amplification; fixed
//      here: store f4 at [64g + T] -> 1KB contiguous per wave instr)
// 4 block barriers total (vs 7 in the 1-butterfly/thread version).
//
// Twiddles: w1 = w_1024^(M*j) from a 256-entry LDS table (max index 255
// in every stage), w2 = w1^2, w3 = w1*w2 (~1 ulp, tol 0.5).

#define N_FFT 1024
#define BATCH 16384
#define TPB   256

typedef float f4 __attribute__((ext_vector_type(4)));

// LDS pad: +1 float2 per 16 slots
__device__ __forceinline__ int pad16(int a) { return a + (a >> 4); }

__device__ __forceinline__ float2 cmul(float2 a, float2 b) {
    return make_float2(a.x * b.x - a.y * b.y, a.x * b.y + a.y * b.x);
}
__device__ __forceinline__ float2 cadd(float2 a, float2 b) { return make_float2(a.x + b.x, a.y + b.y); }
__device__ __forceinline__ float2 csub(float2 a, float2 b) { return make_float2(a.x - b.x, a.y - b.y); }

// Wave-level LDS drain + compiler ordering fence (read->overwrite points;
// write->read points use __syncthreads).
#define LDS_FENCE() do { asm volatile("s_waitcnt lgkmcnt(0)" ::: "memory"); \
                         __builtin_amdgcn_sched_barrier(0); } while (0)

// Radix-4 DIF butterfly, twiddled; in-place: A<-y0, B<-y1, C<-y2, D<-y3.
__device__ __forceinline__ void bf4(float2& A, float2& B, float2& C, float2& D, float2 w1)
{
    float2 t0 = cadd(A, C), t1 = csub(A, C);
    float2 t2 = cadd(B, D);
    float2 t3 = make_float2(B.y - D.y, D.x - B.x);   // -i*(B-D)
    float2 w2 = cmul(w1, w1);
    float2 w3 = cmul(w1, w2);
    A = cadd(t0, t2);
    B = cmul(cadd(t1, t3), w1);
    C = cmul(csub(t0, t2), w2);
    D = cmul(csub(t1, t3), w3);
}
__device__ __forceinline__ void bf4_nw(float2& A, float2& B, float2& C, float2& D)
{
    float2 t0 = cadd(A, C), t1 = csub(A, C);
    float2 t2 = cadd(B, D);
    float2 t3 = make_float2(B.y - D.y, D.x - B.x);
    A = cadd(t0, t2);
    B = cadd(t1, t3);
    C = csub(t0, t2);
    D = csub(t1, t3);
}

__global__ __launch_bounds__(TPB, 4) void fft1024_kernel(
    const float* __restrict__ x,
    const float* __restrict__ twr,   // w_1024^k re, k<512 (first 256 used)
    const float* __restrict__ twi,
    float* __restrict__ outr,
    float* __restrict__ outi)
{
    __shared__ __align__(16) float2 exbuf[4][1088];  // per-wave 1024 + pad
    __shared__ __align__(16) float2 tws[256];        // w_1024^k, k<256

    const int tid = threadIdx.x;
    const int T   = tid & 63;        // lane
    const int wv  = tid >> 6;        // wave in block
    float2* __restrict__ ex = exbuf[wv];

    // twiddle table (wave 0)
    if (tid < 64) {
        f4 re = reinterpret_cast<const f4*>(twr)[tid];
        f4 im = reinterpret_cast<const f4*>(twi)[tid];
        #pragma unroll
        for (int j = 0; j < 4; ++j)
            tws[4 * tid + j] = make_float2(re[j], im[j]);
    }

    const long long r0 = 8LL * blockIdx.x + 2 * wv;  // even row; +1 = odd

    // ---- stage-in: row-pair (2048 floats) via 8 coalesced f4 loads ----
    {
        const f4* __restrict__ xv = reinterpret_cast<const f4*>(x + r0 * N_FFT);
        f4* xs4 = reinterpret_cast<f4*>(ex);
        #pragma unroll
        for (int s = 0; s < 8; ++s)
            xs4[T + 64 * s] = xv[T + 64 * s];
    }
    __syncthreads();   // stage-in + tws visible

    // lane T owns globals {T + 64q}: z[q] = x0[i] + i*x1[i]
    float2 z[16];
    {
        const float* xs = reinterpret_cast<const float*>(ex);
        #pragma unroll
        for (int q = 0; q < 16; ++q)
            z[q] = make_float2(xs[T + 64 * q], xs[1024 + T + 64 * q]);
    }
    LDS_FENCE();       // all stage-in reads drained before exchange-1 writes

    // ---- stage A: M=1 then M=4, in-register ----
    #pragma unroll
    for (int u = 0; u < 4; ++u)
        bf4(z[u], z[u + 4], z[u + 8], z[u + 12], tws[T + 64 * u]);     // M=1: w1=tw[i0]
    {
        float2 wA = tws[4 * T];                                        // M=4: w1=tw[4T]
        #pragma unroll
        for (int r = 0; r < 4; ++r) {
            bf4(z[4 * r], z[4 * r + 1], z[4 * r + 2], z[4 * r + 3], wA);
            ex[pad16(16 * T + r)]      = z[4 * r];
            ex[pad16(16 * T + 4 + r)]  = z[4 * r + 1];
            ex[pad16(16 * T + 8 + r)]  = z[4 * r + 2];
            ex[pad16(16 * T + 12 + r)] = z[4 * r + 3];
        }
    }
    __syncthreads();   // exchange-1 writes -> reads

    #pragma unroll
    for (int q = 0; q < 16; ++q)
        z[q] = ex[pad16(T + 64 * q)];
    LDS_FENCE();       // exchange-1 reads drained before exchange-2 writes

    // ---- stage B: M=16 then M=64, in-register ----
    #pragma unroll
    for (int u = 0; u < 4; ++u)
        bf4(z[u], z[u + 4], z[u + 8], z[u + 12], tws[(T + 64 * u) & ~15]); // M=16
    {
        float2 wB = tws[(T >> 4) << 6];                                    // M=64: w1=tw[64a]
        const int base2 = ((T >> 4) << 8) + (T & 15);                      // 256a + b
        #pragma unroll
        for (int p = 0; p < 4; ++p) {
            bf4(z[4 * p], z[4 * p + 1], z[4 * p + 2], z[4 * p + 3], wB);
            ex[pad16(base2 + 16 * p)]       = z[4 * p];
            ex[pad16(base2 + 16 * p + 64)]  = z[4 * p + 1];
            ex[pad16(base2 + 16 * p + 128)] = z[4 * p + 2];
            ex[pad16(base2 + 16 * p + 192)] = z[4 * p + 3];
        }
    }
    __syncthreads();   // exchange-2 writes -> reads

    // ---- stage C: M=256, unit twiddles; lane-private slots {T+64m} ----
    #pragma unroll
    for (int q = 0; q < 16; ++q)
        z[q] = ex[pad16(T + 64 * q)];
    #pragma unroll
    for (int u = 0; u < 4; ++u) {
        bf4_nw(z[u], z[u + 4], z[u + 8], z[u + 12]);
        ex[pad16(T + 64 * u)]       = z[u];
        ex[pad16(T + 64 * u + 256)] = z[u + 4];
        ex[pad16(T + 64 * u + 512)] = z[u + 8];
        ex[pad16(T + 64 * u + 768)] = z[u + 12];
    }
    __syncthreads();   // stage-C writes -> unpack reads (cross-lane)

    // ---- unpack two real-input spectra; lane-CONTIGUOUS f4 NT stores ----
    // g-loop: lane T handles k in [256g+4T, 256g+4T+4); store f4 at
    // [64g + T] -> wave instruction covers 1KB contiguous per stream.
    f4* or0v = reinterpret_cast<f4*>(outr + r0 * N_FFT);
    f4* oi0v = reinterpret_cast<f4*>(outi + r0 * N_FFT);
    #pragma unroll
    for (int g = 0; g < 4; ++g) {
        const int k0 = 256 * g + 4 * T;       // 4T%16 in {0,4,8,12}: no pad-group crossing
        const int pk = pad16(k0);
        f4 vr0, vi0, vr1, vi1;
        #pragma unroll
        for (int e = 0; e < 4; ++e) {
            const int k  = k0 + e;
            const int nk = (N_FFT - k) & (N_FFT - 1);
            float2 zk = ex[pk + e];           // pad16(k0+e) == pad16(k0)+e
            float2 zn = ex[pad16(nk)];
            // X0 = (Z(k) + conj(Z(-k)))/2 ; X1 = -i*(Z(k) - conj(Z(-k)))/2
            vr0[e] = 0.5f * (zk.x + zn.x);
            vi0[e] = 0.5f * (zk.y - zn.y);
            vr1[e] = 0.5f * (zk.y + zn.y);
            vi1[e] = 0.5f * (zn.x - zk.x);
        }
        __builtin_nontemporal_store(vr0, or0v + 64 * g + T);          // row r0 real
        __builtin_nontemporal_store(vi0, oi0v + 64 * g + T);          // row r0 imag
        __builtin_nontemporal_store(vr1, or0v + 256 + 64 * g + T);    // row r0+1 real
        __builtin_nontemporal_store(vi1, oi0v + 256 + 64 * g + T);    // row r0+1 imag
    }
}

extern "C" void kernel_launch(void* const* d_in, const int* in_sizes, int n_in,
                              void* d_out, int out_size, void* d_ws, size_t ws_size,
                              hipStream_t stream) {
    // setup_inputs order:
    // 0:x 1:perm 2:fft_real 3:fft_imag 4..11: tw_{real,imag}_{0..3}
    const float* x   = (const float*)d_in[0];
    const float* twr = (const float*)d_in[10];  // 512 entries: w_1024^k real
    const float* twi = (const float*)d_in[11];  // 512 entries: w_1024^k imag
    float* outr = (float*)d_out;
    float* outi = outr + (size_t)BATCH * N_FFT;
    fft1024_kernel<<<BATCH / 8, TPB, 0, stream>>>(x, twr, twi, outr, outi);
}